// Round 4
// baseline (214.670 us; speedup 1.0000x reference)
//
#include <hip/hip_runtime.h>
#include <stdint.h>
#include <stddef.h>

typedef __bf16 bf16;
typedef __bf16 bf16x8 __attribute__((ext_vector_type(8)));
typedef float f32x4 __attribute__((ext_vector_type(4)));

// ---------------------------------------------------------------------------
// async global->LDS, 16B per lane. LDS dest is wave-uniform base + lane*16.
// ---------------------------------------------------------------------------
__device__ __forceinline__ void global_to_lds16(const void* g, void* l) {
  const __attribute__((address_space(1))) unsigned* gp =
      reinterpret_cast<const __attribute__((address_space(1))) unsigned*>(
          reinterpret_cast<uintptr_t>(g));
  __attribute__((address_space(3))) unsigned* lp =
      reinterpret_cast<__attribute__((address_space(3))) unsigned*>(
          reinterpret_cast<uintptr_t>(l));
  __builtin_amdgcn_global_load_lds(gp, lp, 16, 0, 0);
}

// ---------------------------------------------------------------------------
// XCD-aware tile swizzle for 64-tile (8x8) GEMMs.
// ---------------------------------------------------------------------------
__device__ __forceinline__ void tile8x8_swizzle(int t, int& bx, int& by) {
  bx = (((t >> 3) & 1) << 2) | (t & 3);
  by = (((t >> 4) & 3) << 1) | ((t >> 2) & 1);
}

// ---------------------------------------------------------------------------
// 128x128-tile NT GEMM body, 256 threads, BK=64, ping-pong LDS (64 KB).
// ROUND-0 PROVEN BODY, byte-for-byte schedule. Used for all tree levels.
// ---------------------------------------------------------------------------
template <typename OutT>
__device__ __forceinline__ void gemm128_body(const bf16* __restrict__ A,
                                             const bf16* __restrict__ B,
                                             OutT* __restrict__ C,
                                             int bx, int by) {
  __shared__ bf16 As[2][128 * 64];   // [buf][half*4096 + row*32 + col]
  __shared__ bf16 Bs[2][128 * 64];

  const int tid = threadIdx.x;
  const int wave = tid >> 6, lane = tid & 63;
  const int quad = lane >> 4, l16 = lane & 15;
  const int rowBase = by * 128;
  const int colBase = bx * 128;
  const int waveM = (wave >> 1) * 64, waveN = (wave & 1) * 64;

  const int sr = tid >> 2;
  const int sc = (tid & 3) * 8;
  const bf16* Ag0 = A + (size_t)(rowBase + sr) * 1024 + sc;   // rows 0..63
  const bf16* Ag1 = Ag0 + (size_t)64 * 1024;                  // rows 64..127
  const bf16* Bg0 = B + (size_t)(colBase + sr) * 1024 + sc;
  const bf16* Bg1 = Bg0 + (size_t)64 * 1024;

  const int woff = wave * 1024;

  auto issue = [&](int k0, int p) {
    char* aB = (char*)As[p] + woff;
    char* bB = (char*)Bs[p] + woff;
    global_to_lds16(Ag0 + k0,      aB);
    global_to_lds16(Ag1 + k0,      aB + 4096);
    global_to_lds16(Ag0 + k0 + 32, aB + 8192);
    global_to_lds16(Ag1 + k0 + 32, aB + 12288);
    global_to_lds16(Bg0 + k0,      bB);
    global_to_lds16(Bg1 + k0,      bB + 4096);
    global_to_lds16(Bg0 + k0 + 32, bB + 8192);
    global_to_lds16(Bg1 + k0 + 32, bB + 12288);
  };

  f32x4 acc[4][4] = {};

  issue(0, 0);
  int p = 0;
#pragma unroll 1
  for (int k0 = 0; k0 < 1024; k0 += 64, p ^= 1) {
    __syncthreads();
    if (k0 + 64 < 1024) issue(k0 + 64, p ^ 1);
#pragma unroll
    for (int kk = 0; kk < 2; kk++) {
      const bf16* base = As[p] + kk * 4096;
      const bf16* baseB = Bs[p] + kk * 4096;
      bf16x8 af[4], bfr[4];
#pragma unroll
      for (int mi = 0; mi < 4; mi++)
        af[mi] = *(const bf16x8*)(base + (waveM + mi * 16 + l16) * 32 + quad * 8);
#pragma unroll
      for (int ni = 0; ni < 4; ni++)
        bfr[ni] = *(const bf16x8*)(baseB + (waveN + ni * 16 + l16) * 32 + quad * 8);
#pragma unroll
      for (int mi = 0; mi < 4; mi++)
#pragma unroll
        for (int ni = 0; ni < 4; ni++)
          acc[mi][ni] = __builtin_amdgcn_mfma_f32_16x16x32_bf16(af[mi], bfr[ni],
                                                                acc[mi][ni], 0, 0, 0);
    }
  }

  OutT* Cb = C + (size_t)(rowBase + waveM) * 1024 + colBase + waveN;
#pragma unroll
  for (int mi = 0; mi < 4; mi++)
#pragma unroll
    for (int ni = 0; ni < 4; ni++)
#pragma unroll
      for (int r = 0; r < 4; r++)
        Cb[(size_t)(mi * 16 + quad * 4 + r) * 1024 + ni * 16 + l16] =
            (OutT)acc[mi][ni][r];
}

// ---------------------------------------------------------------------------
// 128x128-tile NT GEMM, 512 threads / 8 waves (2M x 4N, wave tile 64x32).
// Same LDS layout / staging bytes / K-order as gemm128_body -> bit-identical
// results; just spread over 8 waves so it can live in a 512-thread kernel.
// LDS passed in (As,Bs each 2 x 8192 bf16 = 32 KB).
// ---------------------------------------------------------------------------
template <typename OutT>
__device__ __forceinline__ void gemm128_w8(const bf16* __restrict__ A,
                                           const bf16* __restrict__ B,
                                           OutT* __restrict__ C,
                                           int bx, int by,
                                           bf16* As, bf16* Bs) {
  const int tid = threadIdx.x;            // 0..511
  const int wave = tid >> 6, lane = tid & 63;
  const int quad = lane >> 4, l16 = lane & 15;
  const int rowBase = by * 128, colBase = bx * 128;
  const int waveM = (wave >> 2) * 64;     // 0,64
  const int waveN = (wave & 3) * 32;      // 0,32,64,96

  // staging: one call = 512 thr x 16B = 8 KB = one 128x32 half.
  const int sr = tid >> 2;                // 0..127
  const int sc = (tid & 3) * 8;
  const bf16* Ag = A + (size_t)(rowBase + sr) * 1024 + sc;
  const bf16* Bg = B + (size_t)(colBase + sr) * 1024 + sc;
  const int woff = wave * 1024;

  auto issue = [&](int k0, int p) {
    char* aB = (char*)(As + p * 8192) + woff;
    char* bB = (char*)(Bs + p * 8192) + woff;
    global_to_lds16(Ag + k0,      aB);          // half0
    global_to_lds16(Ag + k0 + 32, aB + 8192);   // half1
    global_to_lds16(Bg + k0,      bB);
    global_to_lds16(Bg + k0 + 32, bB + 8192);
  };

  f32x4 acc[4][2] = {};

  issue(0, 0);
  int p = 0;
#pragma unroll 1
  for (int k0 = 0; k0 < 1024; k0 += 64, p ^= 1) {
    __syncthreads();
    if (k0 + 64 < 1024) issue(k0 + 64, p ^ 1);
#pragma unroll
    for (int kk = 0; kk < 2; kk++) {
      const bf16* base = As + p * 8192 + kk * 4096;
      const bf16* baseB = Bs + p * 8192 + kk * 4096;
      bf16x8 af[4], bfr[2];
#pragma unroll
      for (int mi = 0; mi < 4; mi++)
        af[mi] = *(const bf16x8*)(base + (waveM + mi * 16 + l16) * 32 + quad * 8);
#pragma unroll
      for (int ni = 0; ni < 2; ni++)
        bfr[ni] = *(const bf16x8*)(baseB + (waveN + ni * 16 + l16) * 32 + quad * 8);
#pragma unroll
      for (int mi = 0; mi < 4; mi++)
#pragma unroll
        for (int ni = 0; ni < 2; ni++)
          acc[mi][ni] = __builtin_amdgcn_mfma_f32_16x16x32_bf16(af[mi], bfr[ni],
                                                                acc[mi][ni], 0, 0, 0);
    }
  }

  OutT* Cb = C + (size_t)(rowBase + waveM) * 1024 + colBase + waveN;
#pragma unroll
  for (int mi = 0; mi < 4; mi++)
#pragma unroll
    for (int ni = 0; ni < 2; ni++)
#pragma unroll
      for (int r = 0; r < 4; r++)
        Cb[(size_t)(mi * 16 + quad * 4 + r) * 1024 + ni * 16 + l16] =
            (OutT)acc[mi][ni][r];
}

// ---------------------------------------------------------------------------
// 256x256-tile NT GEMM, 512 threads / 8 waves (4M x 2N, wave tile 64x128),
// BK=32, ping-pong LDS (64 KB). 16 B of staged bytes per output element --
// HALF the 128-tile body's 32 B. This is the fix for the staging-BW-bound
// big GEMMs (rocprof r1: 288 MB staged in 41 us = 7 TB/s = L2/L3 ceiling;
// MfmaUtil 16%, HBM 15% -> neither MFMA- nor HBM-bound).
//
// LDS: [row][32] bf16 rows (64 B), granule (16 B) XOR-swizzle
//   LDS(r,g) = GLOBAL(r, g ^ ((r>>1)&3))
// applied rule-21 style: linear global_load_lds dest + inverse-swizzled
// per-lane SOURCE address; ds_reads XOR their granule with (l16>>1)&3.
// Within each 16-lane read group the 8 even(/odd) lanes then cover banks
// 0-15(/16-31) exactly twice -> 2-way = free.
// K-accumulation: 32 iters x one K=32 MFMA, ascending -- same FP order as
// the 128-tile bodies.
// ---------------------------------------------------------------------------
template <typename OutT>
__device__ __forceinline__ void gemm256_body(const bf16* __restrict__ A,
                                             const bf16* __restrict__ B,
                                             OutT* __restrict__ C,
                                             int bx, int by,
                                             bf16* As, bf16* Bs) {
  const int tid = threadIdx.x;            // 0..511
  const int wave = tid >> 6, lane = tid & 63;
  const int quad = lane >> 4, l16 = lane & 15;
  const int rowBase = by * 256, colBase = bx * 256;
  const int waveM = (wave >> 1) * 64;     // 0,64,128,192
  const int waveN = (wave & 1) * 128;     // 0,128

  // staging: call c covers rows [128c,128c+128): thread t -> row t>>2,
  // source granule (t&3)^((t>>3)&3)  (inverse swizzle; (r>>1)&3 == (t>>3)&3).
  const int sr = tid >> 2;                        // 0..127
  const int sg = (tid & 3) ^ ((tid >> 3) & 3);    // 0..3
  const bf16* Ag  = A + (size_t)(rowBase + sr) * 1024 + sg * 8;
  const bf16* Ag1 = Ag + (size_t)128 * 1024;
  const bf16* Bg  = B + (size_t)(colBase + sr) * 1024 + sg * 8;
  const bf16* Bg1 = Bg + (size_t)128 * 1024;
  const int woff = wave * 1024;

  auto issue = [&](int k0, int p) {
    char* aB = (char*)(As + p * 8192) + woff;
    char* bB = (char*)(Bs + p * 8192) + woff;
    global_to_lds16(Ag  + k0, aB);           // rows 0..127
    global_to_lds16(Ag1 + k0, aB + 8192);    // rows 128..255
    global_to_lds16(Bg  + k0, bB);
    global_to_lds16(Bg1 + k0, bB + 8192);
  };

  f32x4 acc[4][8] = {};

  issue(0, 0);
  int p = 0;
  const int gsw = (quad ^ ((l16 >> 1) & 3)) * 8;   // swizzled read granule
#pragma unroll 1
  for (int i = 0; i < 32; ++i, p ^= 1) {
    __syncthreads();                 // drains loads for tile i (buf p)
    if (i + 1 < 32) issue((i + 1) * 32, p ^ 1);
    const bf16* bA = As + p * 8192;
    const bf16* bB = Bs + p * 8192;
    bf16x8 af[4], bfr[8];
#pragma unroll
    for (int mi = 0; mi < 4; mi++)
      af[mi] = *(const bf16x8*)(bA + (waveM + mi * 16 + l16) * 32 + gsw);
#pragma unroll
    for (int ni = 0; ni < 8; ni++)
      bfr[ni] = *(const bf16x8*)(bB + (waveN + ni * 16 + l16) * 32 + gsw);
#pragma unroll
    for (int mi = 0; mi < 4; mi++)
#pragma unroll
      for (int ni = 0; ni < 8; ni++)
        acc[mi][ni] = __builtin_amdgcn_mfma_f32_16x16x32_bf16(af[mi], bfr[ni],
                                                              acc[mi][ni], 0, 0, 0);
  }

  OutT* Cb = C + (size_t)(rowBase + waveM) * 1024 + colBase + waveN;
#pragma unroll
  for (int mi = 0; mi < 4; mi++)
#pragma unroll
    for (int ni = 0; ni < 8; ni++)
#pragma unroll
      for (int r = 0; r < 4; r++)
        Cb[(size_t)(mi * 16 + quad * 4 + r) * 1024 + ni * 16 + l16] =
            (OutT)acc[mi][ni][r];
}

// ---------------------------------------------------------------------------
// fused prep kernel (unchanged round-0). 5120 x 256 threads.
// ---------------------------------------------------------------------------
struct PrepArgs {
  const float* cvt_src[5]; bf16* cvt_dst[5];
  const float* tr_src[6];  bf16* tr_dst[6];
  const float* Wdec; const int* praw; bf16* Gbf;
};

__global__ __launch_bounds__(256) void prep_all(PrepArgs p) {
  __shared__ alignas(16) char smem[64 * 65 * 2];
  const int b = blockIdx.x;
  const int tid = threadIdx.x;

  if (b < 2560) {  // ---- convert row-major W ----
    const int m = b >> 9, blk = b & 511;
    const float* __restrict__ src = p.cvt_src[m];
    bf16* __restrict__ dst = p.cvt_dst[m];
    const int i = (blk * 256 + tid) * 8;
    float4 a = *(const float4*)(src + i);
    float4 c = *(const float4*)(src + i + 4);
    bf16x8 o;
    o[0] = (bf16)a.x; o[1] = (bf16)a.y; o[2] = (bf16)a.z; o[3] = (bf16)a.w;
    o[4] = (bf16)c.x; o[5] = (bf16)c.y; o[6] = (bf16)c.z; o[7] = (bf16)c.w;
    *(bf16x8*)(dst + i) = o;
  } else if (b < 4096) {  // ---- transpose+convert W ----
    const int t = b - 2560;
    const int m = t >> 8, r = t & 255;
    const float* __restrict__ src = p.tr_src[m];
    bf16* __restrict__ dst = p.tr_dst[m];
    bf16(*tile)[65] = reinterpret_cast<bf16(*)[65]>(smem);
    const int bx = (r & 15) * 64;
    const int by = (r >> 4) * 64;
    const int tx = tid & 63;
    const int ty4 = tid >> 6;
#pragma unroll
    for (int rr = 0; rr < 16; rr++) {
      int row = ty4 * 16 + rr;
      tile[row][tx] = (bf16)src[(size_t)(by + row) * 1024 + bx + tx];
    }
    __syncthreads();
#pragma unroll
    for (int rr = 0; rr < 16; rr++) {
      int row = ty4 * 16 + rr;
      dst[(size_t)(bx + row) * 1024 + by + tx] = tile[tx][row];
    }
  } else {  // ---- G build: G[j,d] = sum_{k: perm[k]==d} W_dec[j,k] ----
    const int j = b - 4096;
    float* row = (float*)smem;
    int* perm_l = (int*)(smem + 4096);
    int* nzp = (int*)(smem + 4096 + 1024);
#pragma unroll
    for (int c = 0; c < 4; c++) row[tid * 4 + c] = 0.f;
    if (tid == 0) *nzp = 0;
    __syncthreads();
    if (tid < 128 && p.praw[2 * tid + 1] != 0) atomicOr(nzp, 1);
    __syncthreads();
    const int is64 = (*nzp == 0);
    perm_l[tid] = is64 ? p.praw[2 * tid] : p.praw[tid];
    __syncthreads();
    atomicAdd(&row[perm_l[tid]], p.Wdec[(size_t)j * 256 + tid]);
    __syncthreads();
#pragma unroll
    for (int c = 0; c < 4; c++)
      p.Gbf[(size_t)j * 1024 + tid * 4 + c] = (bf16)row[tid * 4 + c];
  }
}

// ---------------------------------------------------------------------------
// Tree-level kernel (256 thr): blocks [0, nG*64) batched 128-tile NT GEMMs;
// blocks >= nG*64 each convert EIGHT 2048-float x-units fp32->bf16.
// ---------------------------------------------------------------------------
struct TreeArgs {
  const bf16* A[6]; const bf16* B[6]; bf16* C[6];
  int nG;
  const float* x; bf16* xbf; int ubase;
};

__global__ __launch_bounds__(256) void tree_level(TreeArgs a) {
  const int b = blockIdx.x;
  const int gBlocks = a.nG * 64;
  if (b < gBlocks) {
    const int z = b >> 6, t = b & 63;
    int bx, by;
    tile8x8_swizzle(t, bx, by);
    gemm128_body<bf16>(a.A[z], a.B[z], a.C[z], bx, by);
  } else {
    const int u0 = a.ubase + (b - gBlocks) * 8;
#pragma unroll
    for (int u = 0; u < 8; u++) {
      const int i = (u0 + u) * 2048 + (int)threadIdx.x * 8;
      float4 v0 = *(const float4*)(a.x + i);
      float4 v1 = *(const float4*)(a.x + i + 4);
      bf16x8 o;
      o[0] = (bf16)v0.x; o[1] = (bf16)v0.y; o[2] = (bf16)v0.z; o[3] = (bf16)v0.w;
      o[4] = (bf16)v1.x; o[5] = (bf16)v1.y; o[6] = (bf16)v1.z; o[7] = (bf16)v1.w;
      *(bf16x8*)(a.xbf + i) = o;
    }
  }
}

// ---------------------------------------------------------------------------
// Step 4 (512 thr): blocks 0..63: A8 = NT(Q0,Q1t) via the 128-tile body
// (latency-bound, hidden under S1). Blocks 64..191: S1 = NT(xbf, C4) via
// the 256-tile body (staging-BW-optimal). 64 KB shared carved for either.
// ---------------------------------------------------------------------------
struct L3SArgs {
  const bf16* Q0; const bf16* Q1t; bf16* A8;
  const bf16* xbf; const bf16* C4; bf16* S1;
};

__global__ __launch_bounds__(512, 2) void l3s_level(L3SArgs a) {
  __shared__ bf16 smem[32768];   // 64 KB
  bf16* As = smem;
  bf16* Bs = smem + 16384;
  const int b = blockIdx.x;
  if (b < 64) {
    int bx, by;
    tile8x8_swizzle(b, bx, by);
    gemm128_w8<bf16>(a.Q0, a.Q1t, a.A8, bx, by, As, Bs);
  } else {
    const int t = b - 64;                       // 0..127
    const int by = (t & 7) * 4 + ((t >> 3) & 3);  // XCD k: 4 contiguous panels
    const int bx = t >> 5;
    gemm256_body<bf16>(a.xbf, a.C4, a.S1, bx, by, As, Bs);
  }
}

// ---------------------------------------------------------------------------
// Final (512 thr): out = S1 * A8^T, fp32 out. M=8192,N=1024,K=1024.
// 128 tiles of 256x256. XCD k owns 4 contiguous by-panels (2 MB) + A8 (2 MB).
// ---------------------------------------------------------------------------
__global__ __launch_bounds__(512, 2) void final_gemm(const bf16* __restrict__ A,
                                                     const bf16* __restrict__ B,
                                                     float* __restrict__ C) {
  __shared__ bf16 smem[32768];
  const int b = blockIdx.x;
  const int by = (b & 7) * 4 + ((b >> 3) & 3);
  const int bx = b >> 5;
  gemm256_body<float>(A, B, C, bx, by, smem, smem + 16384);
}

// ---------------------------------------------------------------------------
// Host launcher. 5 kernels.
// F = A8 * C4 with A8 = G*W9*W8*W8*W7*W6*W5*W4, C4 = W3*W2*W1*W0.
// Tree: P0=G*W9 P1=(W8W8)^T P2=W7*W6 P3=(W5W4)^T P4=W3*W2 P5=(W1W0)^T
//       Q0=NT(P0,P1) Q1t=NT(P3,P2) C4=NT(P4,P5)
//       step4: A8=NT(Q0,Q1t) || S1=NT(xbf,C4)      (concurrent)
//       out = NT(S1, A8)  =  x * F^T.
// x-convert spread across L1/L2 filler blocks (done before step 4).
// ---------------------------------------------------------------------------
extern "C" void kernel_launch(void* const* d_in, const int* in_sizes, int n_in,
                              void* d_out, int out_size, void* d_ws, size_t ws_size,
                              hipStream_t stream) {
  const float* x    = (const float*)d_in[0];
  const float* Wsrc = (const float*)d_in[1];   // 10 x 1024 x 1024
  const float* Wdec = (const float*)d_in[2];   // 1024 x 256
  const int*   praw = (const int*)d_in[3];
  float* out = (float*)d_out;

  constexpr size_t MAT  = 1024ull * 1024ull;
  constexpr size_t SLOT = 2ull * 1024 * 1024;  // 2 MiB = one bf16 DxD matrix

  char* ws = (char*)d_ws;
  bf16* Wrm[5];  // W1, W3, W5, W7, W8 (row-major bf16)
  for (int i = 0; i < 5; i++) Wrm[i] = (bf16*)(ws + (size_t)i * SLOT);
  bf16* Wt[6];   // W0^T, W2^T, W4^T, W6^T, W8^T, W9^T
  for (int i = 0; i < 6; i++) Wt[i] = (bf16*)(ws + (size_t)(5 + i) * SLOT);
  bf16* Gbf = (bf16*)(ws + 11 * SLOT);
  bf16* xbf = (bf16*)(ws + 12 * SLOT);         // 8 slots (16 MiB)
  bf16* P[6];
  for (int i = 0; i < 6; i++) P[i] = (bf16*)(ws + (size_t)(20 + i) * SLOT);
  bf16* Q[3];                                   // Q0, Q1t, C4
  for (int i = 0; i < 3; i++) Q[i] = (bf16*)(ws + (size_t)(26 + i) * SLOT);
  bf16* A8b = (bf16*)(ws + 29 * SLOT);
  bf16* S1b = (bf16*)(ws + 30 * SLOT);         // 8 slots; total ws use: 76 MiB

  // 1) fused prep (W converts, W transposes, G)
  PrepArgs pa;
  const int rmIdx[5] = {1, 3, 5, 7, 8};
  for (int i = 0; i < 5; i++) { pa.cvt_src[i] = Wsrc + (size_t)rmIdx[i] * MAT; pa.cvt_dst[i] = Wrm[i]; }
  const int trIdx[6] = {0, 2, 4, 6, 8, 9};
  for (int i = 0; i < 6; i++) { pa.tr_src[i] = Wsrc + (size_t)trIdx[i] * MAT; pa.tr_dst[i] = Wt[i]; }
  pa.Wdec = Wdec; pa.praw = praw; pa.Gbf = Gbf;
  prep_all<<<dim3(5120), 256, 0, stream>>>(pa);

  // 2) L1: 6 GEMMs (384 blocks) + xcvt units [0,2048) as 256 8-unit blocks
  TreeArgs L1{};
  const bf16* l1a[6] = {Gbf, Wt[4], Wrm[3], Wt[2], Wrm[1], Wt[0]};
  const bf16* l1b[6] = {Wt[5], Wrm[4], Wt[3], Wrm[2], Wt[1], Wrm[0]};
  for (int i = 0; i < 6; i++) { L1.A[i] = l1a[i]; L1.B[i] = l1b[i]; L1.C[i] = P[i]; }
  L1.nG = 6; L1.x = x; L1.xbf = xbf; L1.ubase = 0;
  tree_level<<<dim3(384 + 256), 256, 0, stream>>>(L1);

  // 3) L2: Q0=NT(P0,P1) Q1t=NT(P3,P2) C4=NT(P4,P5) + xcvt units [2048,4096)
  TreeArgs L2{};
  const bf16* l2a[3] = {P[0], P[3], P[4]};
  const bf16* l2b[3] = {P[1], P[2], P[5]};
  for (int i = 0; i < 3; i++) { L2.A[i] = l2a[i]; L2.B[i] = l2b[i]; L2.C[i] = Q[i]; }
  L2.nG = 3; L2.x = x; L2.xbf = xbf; L2.ubase = 2048;
  tree_level<<<dim3(192 + 256), 256, 0, stream>>>(L2);

  // 4) step 4: A8 = NT(Q0,Q1t) [blocks 0..63] || S1 = NT(xbf,C4) [64..191]
  L3SArgs l3;
  l3.Q0 = Q[0]; l3.Q1t = Q[1]; l3.A8 = A8b;
  l3.xbf = xbf; l3.C4 = Q[2];  l3.S1 = S1b;
  l3s_level<<<dim3(192), 512, 0, stream>>>(l3);

  // 5) out = NT(S1, A8), fp32 out (128 tiles of 256x256, XCD-partitioned)
  final_gemm<<<dim3(128), 512, 0, stream>>>(S1b, A8b, out);

  (void)in_sizes; (void)n_in; (void)out_size; (void)ws_size;
}

// Round 6
// 193.251 us; speedup vs baseline: 1.1108x; 1.1108x over previous
//
#include <hip/hip_runtime.h>
#include <stdint.h>
#include <stddef.h>

typedef __bf16 bf16;
typedef __bf16 bf16x8 __attribute__((ext_vector_type(8)));
typedef float f32x4 __attribute__((ext_vector_type(4)));

// ---------------------------------------------------------------------------
// async global->LDS, 16B per lane. LDS dest is wave-uniform base + lane*16.
// ---------------------------------------------------------------------------
__device__ __forceinline__ void global_to_lds16(const void* g, void* l) {
  const __attribute__((address_space(1))) unsigned* gp =
      reinterpret_cast<const __attribute__((address_space(1))) unsigned*>(
          reinterpret_cast<uintptr_t>(g));
  __attribute__((address_space(3))) unsigned* lp =
      reinterpret_cast<__attribute__((address_space(3))) unsigned*>(
          reinterpret_cast<uintptr_t>(l));
  __builtin_amdgcn_global_load_lds(gp, lp, 16, 0, 0);
}

// ---------------------------------------------------------------------------
// XCD-aware tile swizzle for 64-tile (8x8) GEMMs.
// ---------------------------------------------------------------------------
__device__ __forceinline__ void tile8x8_swizzle(int t, int& bx, int& by) {
  bx = (((t >> 3) & 1) << 2) | (t & 3);
  by = (((t >> 4) & 3) << 1) | ((t >> 2) & 1);
}

// ---------------------------------------------------------------------------
// 128x128-tile NT GEMM body, BK=64, PING-PONG double-buffered LDS (64 KB).
// R0 PROVEN BODY (197 us baseline) -- byte-for-byte unchanged.
// ---------------------------------------------------------------------------
template <typename OutT>
__device__ __forceinline__ void gemm128_body(const bf16* __restrict__ A,
                                             const bf16* __restrict__ B,
                                             OutT* __restrict__ C,
                                             int bx, int by) {
  __shared__ bf16 As[2][128 * 64];   // [buf][half*4096 + row*32 + col]
  __shared__ bf16 Bs[2][128 * 64];

  const int tid = threadIdx.x;
  const int wave = tid >> 6, lane = tid & 63;
  const int quad = lane >> 4, l16 = lane & 15;
  const int rowBase = by * 128;
  const int colBase = bx * 128;
  const int waveM = (wave >> 1) * 64, waveN = (wave & 1) * 64;

  // staging map: thread t covers global row t/4, cols (t&3)*8 .. +7
  const int sr = tid >> 2;
  const int sc = (tid & 3) * 8;
  const bf16* Ag0 = A + (size_t)(rowBase + sr) * 1024 + sc;   // rows 0..63
  const bf16* Ag1 = Ag0 + (size_t)64 * 1024;                  // rows 64..127
  const bf16* Bg0 = B + (size_t)(colBase + sr) * 1024 + sc;
  const bf16* Bg1 = Bg0 + (size_t)64 * 1024;

  const int woff = wave * 1024;  // byte offset of this wave's 16-row slab

  auto issue = [&](int k0, int p) {
    char* aB = (char*)As[p] + woff;
    char* bB = (char*)Bs[p] + woff;
    global_to_lds16(Ag0 + k0,      aB);             // half0 rows 0..63
    global_to_lds16(Ag1 + k0,      aB + 4096);      // half0 rows 64..127
    global_to_lds16(Ag0 + k0 + 32, aB + 8192);      // half1 rows 0..63
    global_to_lds16(Ag1 + k0 + 32, aB + 12288);     // half1 rows 64..127
    global_to_lds16(Bg0 + k0,      bB);
    global_to_lds16(Bg1 + k0,      bB + 4096);
    global_to_lds16(Bg0 + k0 + 32, bB + 8192);
    global_to_lds16(Bg1 + k0 + 32, bB + 12288);
  };

  f32x4 acc[4][4] = {};

  issue(0, 0);
  int p = 0;
#pragma unroll 1
  for (int k0 = 0; k0 < 1024; k0 += 64, p ^= 1) {
    __syncthreads();                 // drains loads for tile k0 (buf p)
    if (k0 + 64 < 1024) issue(k0 + 64, p ^ 1);   // prefetch into other buf
#pragma unroll
    for (int kk = 0; kk < 2; kk++) {
      const bf16* base = As[p] + kk * 4096;
      const bf16* baseB = Bs[p] + kk * 4096;
      bf16x8 af[4], bfr[4];
#pragma unroll
      for (int mi = 0; mi < 4; mi++)
        af[mi] = *(const bf16x8*)(base + (waveM + mi * 16 + l16) * 32 + quad * 8);
#pragma unroll
      for (int ni = 0; ni < 4; ni++)
        bfr[ni] = *(const bf16x8*)(baseB + (waveN + ni * 16 + l16) * 32 + quad * 8);
#pragma unroll
      for (int mi = 0; mi < 4; mi++)
#pragma unroll
        for (int ni = 0; ni < 4; ni++)
          acc[mi][ni] = __builtin_amdgcn_mfma_f32_16x16x32_bf16(af[mi], bfr[ni],
                                                                acc[mi][ni], 0, 0, 0);
    }
  }

  OutT* Cb = C + (size_t)(rowBase + waveM) * 1024 + colBase + waveN;
#pragma unroll
  for (int mi = 0; mi < 4; mi++)
#pragma unroll
    for (int ni = 0; ni < 4; ni++)
#pragma unroll
      for (int r = 0; r < 4; r++)
        Cb[(size_t)(mi * 16 + quad * 4 + r) * 1024 + ni * 16 + l16] =
            (OutT)acc[mi][ni][r];
}

// ---------------------------------------------------------------------------
// 128x64-tile NT GEMM body: minimal-diff derivative of gemm128_body with the
// N-extent halved (B-tile 64 rows, Bs 8 KB/buffer, LDS total 48 KB -> 3
// blocks/CU). Same staging pattern, same BK=64 / kk / MFMA K-order -> each
// output element's accumulation chain is bit-identical to gemm128_body.
// Purpose: L3/L4 run 1024^2 outputs as 128 blocks (vs 64) -- these stages
// are latency-bound with NO filler in R0 (75% of CUs idle); doubling block
// count + 3/CU residency attacks exactly that.
// ---------------------------------------------------------------------------
template <typename OutT>
__device__ __forceinline__ void gemm128x64_body(const bf16* __restrict__ A,
                                                const bf16* __restrict__ B,
                                                OutT* __restrict__ C,
                                                int bx, int by) {
  __shared__ bf16 As[2][128 * 64];   // 16 KB per buffer (unchanged)
  __shared__ bf16 Bs[2][64 * 64];    // 8 KB per buffer

  const int tid = threadIdx.x;
  const int wave = tid >> 6, lane = tid & 63;
  const int quad = lane >> 4, l16 = lane & 15;
  const int rowBase = by * 128;
  const int colBase = bx * 64;
  const int waveM = (wave >> 1) * 64;   // 0,64
  const int waveN = (wave & 1) * 32;    // 0,32

  const int sr = tid >> 2;
  const int sc = (tid & 3) * 8;
  const bf16* Ag0 = A + (size_t)(rowBase + sr) * 1024 + sc;   // rows 0..63
  const bf16* Ag1 = Ag0 + (size_t)64 * 1024;                  // rows 64..127
  const bf16* Bg0 = B + (size_t)(colBase + sr) * 1024 + sc;   // rows 0..63

  const int woff = wave * 1024;

  auto issue = [&](int k0, int p) {
    char* aB = (char*)As[p] + woff;
    char* bB = (char*)Bs[p] + woff;
    global_to_lds16(Ag0 + k0,      aB);             // half0 rows 0..63
    global_to_lds16(Ag1 + k0,      aB + 4096);      // half0 rows 64..127
    global_to_lds16(Ag0 + k0 + 32, aB + 8192);      // half1 rows 0..63
    global_to_lds16(Ag1 + k0 + 32, aB + 12288);     // half1 rows 64..127
    global_to_lds16(Bg0 + k0,      bB);             // half0 rows 0..63
    global_to_lds16(Bg0 + k0 + 32, bB + 4096);      // half1 rows 0..63
  };

  f32x4 acc[4][2] = {};

  issue(0, 0);
  int p = 0;
#pragma unroll 1
  for (int k0 = 0; k0 < 1024; k0 += 64, p ^= 1) {
    __syncthreads();
    if (k0 + 64 < 1024) issue(k0 + 64, p ^ 1);
#pragma unroll
    for (int kk = 0; kk < 2; kk++) {
      const bf16* base = As[p] + kk * 4096;
      const bf16* baseB = Bs[p] + kk * 2048;
      bf16x8 af[4], bfr[2];
#pragma unroll
      for (int mi = 0; mi < 4; mi++)
        af[mi] = *(const bf16x8*)(base + (waveM + mi * 16 + l16) * 32 + quad * 8);
#pragma unroll
      for (int ni = 0; ni < 2; ni++)
        bfr[ni] = *(const bf16x8*)(baseB + (waveN + ni * 16 + l16) * 32 + quad * 8);
#pragma unroll
      for (int mi = 0; mi < 4; mi++)
#pragma unroll
        for (int ni = 0; ni < 2; ni++)
          acc[mi][ni] = __builtin_amdgcn_mfma_f32_16x16x32_bf16(af[mi], bfr[ni],
                                                                acc[mi][ni], 0, 0, 0);
    }
  }

  OutT* Cb = C + (size_t)(rowBase + waveM) * 1024 + colBase + waveN;
#pragma unroll
  for (int mi = 0; mi < 4; mi++)
#pragma unroll
    for (int ni = 0; ni < 2; ni++)
#pragma unroll
      for (int r = 0; r < 4; r++)
        Cb[(size_t)(mi * 16 + quad * 4 + r) * 1024 + ni * 16 + l16] =
            (OutT)acc[mi][ni][r];
}

// ---------------------------------------------------------------------------
// fused prep kernel (unchanged R0). Flat grid of 5120 independent blocks.
// ---------------------------------------------------------------------------
struct PrepArgs {
  const float* cvt_src[5]; bf16* cvt_dst[5];
  const float* tr_src[6];  bf16* tr_dst[6];
  const float* Wdec; const int* praw; bf16* Gbf;
};

__global__ __launch_bounds__(256) void prep_all(PrepArgs p) {
  __shared__ alignas(16) char smem[64 * 65 * 2];
  const int b = blockIdx.x;
  const int tid = threadIdx.x;

  if (b < 2560) {  // ---- convert row-major W ----
    const int m = b >> 9, blk = b & 511;
    const float* __restrict__ src = p.cvt_src[m];
    bf16* __restrict__ dst = p.cvt_dst[m];
    const int i = (blk * 256 + tid) * 8;
    float4 a = *(const float4*)(src + i);
    float4 c = *(const float4*)(src + i + 4);
    bf16x8 o;
    o[0] = (bf16)a.x; o[1] = (bf16)a.y; o[2] = (bf16)a.z; o[3] = (bf16)a.w;
    o[4] = (bf16)c.x; o[5] = (bf16)c.y; o[6] = (bf16)c.z; o[7] = (bf16)c.w;
    *(bf16x8*)(dst + i) = o;
  } else if (b < 4096) {  // ---- transpose+convert W ----
    const int t = b - 2560;
    const int m = t >> 8, r = t & 255;
    const float* __restrict__ src = p.tr_src[m];
    bf16* __restrict__ dst = p.tr_dst[m];
    bf16(*tile)[65] = reinterpret_cast<bf16(*)[65]>(smem);
    const int bx = (r & 15) * 64;
    const int by = (r >> 4) * 64;
    const int tx = tid & 63;
    const int ty4 = tid >> 6;
#pragma unroll
    for (int rr = 0; rr < 16; rr++) {
      int row = ty4 * 16 + rr;
      tile[row][tx] = (bf16)src[(size_t)(by + row) * 1024 + bx + tx];
    }
    __syncthreads();
#pragma unroll
    for (int rr = 0; rr < 16; rr++) {
      int row = ty4 * 16 + rr;
      dst[(size_t)(bx + row) * 1024 + by + tx] = tile[tx][row];
    }
  } else {  // ---- G build: G[j,d] = sum_{k: perm[k]==d} W_dec[j,k] ----
    const int j = b - 4096;
    float* row = (float*)smem;
    int* perm_l = (int*)(smem + 4096);
    int* nzp = (int*)(smem + 4096 + 1024);
#pragma unroll
    for (int c = 0; c < 4; c++) row[tid * 4 + c] = 0.f;
    if (tid == 0) *nzp = 0;
    __syncthreads();
    // int64 little-endian perm has all-zero high words.
    if (tid < 128 && p.praw[2 * tid + 1] != 0) atomicOr(nzp, 1);
    __syncthreads();
    const int is64 = (*nzp == 0);
    perm_l[tid] = is64 ? p.praw[2 * tid] : p.praw[tid];
    __syncthreads();
    atomicAdd(&row[perm_l[tid]], p.Wdec[(size_t)j * 256 + tid]);
    __syncthreads();
#pragma unroll
    for (int c = 0; c < 4; c++)
      p.Gbf[(size_t)j * 1024 + tid * 4 + c] = (bf16)row[tid * 4 + c];
  }
}

// ---------------------------------------------------------------------------
// Tree-level kernel (unchanged R0): blocks [0, nG*64) do batched 128x128-tile
// NT GEMMs with XCD-aware tile swizzle; blocks >= nG*64 each convert EIGHT
// 2048-float x-units fp32->bf16.
// ---------------------------------------------------------------------------
struct TreeArgs {
  const bf16* A[6]; const bf16* B[6]; bf16* C[6];
  int nG;
  const float* x; bf16* xbf; int ubase;
};

__global__ __launch_bounds__(256) void tree_level(TreeArgs a) {
  const int b = blockIdx.x;
  const int gBlocks = a.nG * 64;
  if (b < gBlocks) {
    const int z = b >> 6, t = b & 63;
    int bx, by;
    tile8x8_swizzle(t, bx, by);
    gemm128_body<bf16>(a.A[z], a.B[z], a.C[z], bx, by);
  } else {
    const int u0 = a.ubase + (b - gBlocks) * 8;
#pragma unroll
    for (int u = 0; u < 8; u++) {
      const int i = (u0 + u) * 2048 + (int)threadIdx.x * 8;
      float4 v0 = *(const float4*)(a.x + i);
      float4 v1 = *(const float4*)(a.x + i + 4);
      bf16x8 o;
      o[0] = (bf16)v0.x; o[1] = (bf16)v0.y; o[2] = (bf16)v0.z; o[3] = (bf16)v0.w;
      o[4] = (bf16)v1.x; o[5] = (bf16)v1.y; o[6] = (bf16)v1.z; o[7] = (bf16)v1.w;
      *(bf16x8*)(a.xbf + i) = o;
    }
  }
}

// ---------------------------------------------------------------------------
// Half-N tree-level kernel for the single-GEMM stages L3/L4: blocks [0,128)
// do one 1024^2 NT GEMM as 128x64 tiles (2x the block count of the 128^2
// version -> 2x CU coverage at a latency-bound stage; 48 KB LDS -> 3
// blocks/CU). Flat mapping by = b&7, bx = b>>3: XCD k owns A-panel k
// (256 KB) + all of B (2 MB). Blocks >= 128 do x-convert filler.
// ---------------------------------------------------------------------------
__global__ __launch_bounds__(256) void tree_level_hn(TreeArgs a) {
  const int b = blockIdx.x;
  if (b < 128) {
    gemm128x64_body<bf16>(a.A[0], a.B[0], a.C[0], b >> 3, b & 7);
  } else {
    const int u0 = a.ubase + (b - 128) * 8;
#pragma unroll
    for (int u = 0; u < 8; u++) {
      const int i = (u0 + u) * 2048 + (int)threadIdx.x * 8;
      float4 v0 = *(const float4*)(a.x + i);
      float4 v1 = *(const float4*)(a.x + i + 4);
      bf16x8 o;
      o[0] = (bf16)v0.x; o[1] = (bf16)v0.y; o[2] = (bf16)v0.z; o[3] = (bf16)v0.w;
      o[4] = (bf16)v1.x; o[5] = (bf16)v1.y; o[6] = (bf16)v1.z; o[7] = (bf16)v1.w;
      *(bf16x8*)(a.xbf + i) = o;
    }
  }
}

// ---------------------------------------------------------------------------
// Final: out = x * F^T, fp32 out. M=8192, N=1024, K=1024. Flat 512-block
// grid with bx = b>>6, by = b&63 (unchanged R0).
// ---------------------------------------------------------------------------
__global__ __launch_bounds__(256) void final_gemm(const bf16* __restrict__ A,
                                                  const bf16* __restrict__ B,
                                                  float* __restrict__ C) {
  const int b = blockIdx.x;
  gemm128_body<float>(A, B, C, b >> 6, b & 63);
}

// ---------------------------------------------------------------------------
// Host launcher.  6 kernels.
// out = x @ (G * W9 * W8 * W8 * W7 * W6 * W5 * W4 * W3 * W2 * W1 * W0)^T
// Tree: P0=G*W9  P1=(W8*W8)^T  P2=W7*W6  P3=(W5*W4)^T  P4=W3*W2  P5=(W1*W0)^T
//       Q0=NT(P0,P1) Q1t=NT(P3,P2) Q2t=NT(P5,P4); R=NT(Q0,Q1t); F=NT(R,Q2t)
//       out = NT(x, F).
// x convert filler: 2048 units in L1, 1024 in L2, 512 in L3, 512 in L4 --
// every stage keeps all CUs fed (R0 left L3/L4 at 25% CU coverage, no filler).
// ---------------------------------------------------------------------------
extern "C" void kernel_launch(void* const* d_in, const int* in_sizes, int n_in,
                              void* d_out, int out_size, void* d_ws, size_t ws_size,
                              hipStream_t stream) {
  const float* x    = (const float*)d_in[0];
  const float* Wsrc = (const float*)d_in[1];   // 10 x 1024 x 1024
  const float* Wdec = (const float*)d_in[2];   // 1024 x 256
  const int*   praw = (const int*)d_in[3];
  float* out = (float*)d_out;

  constexpr size_t MAT  = 1024ull * 1024ull;
  constexpr size_t SLOT = 2ull * 1024 * 1024;  // 2 MiB = one bf16 DxD matrix

  char* ws = (char*)d_ws;
  bf16* Wrm[5];  // W1, W3, W5, W7, W8 (row-major bf16)
  for (int i = 0; i < 5; i++) Wrm[i] = (bf16*)(ws + (size_t)i * SLOT);
  bf16* Wt[6];   // W0^T, W2^T, W4^T, W6^T, W8^T, W9^T
  for (int i = 0; i < 6; i++) Wt[i] = (bf16*)(ws + (size_t)(5 + i) * SLOT);
  bf16* Gbf = (bf16*)(ws + 11 * SLOT);
  bf16* xbf = (bf16*)(ws + 12 * SLOT);         // 8 slots (16 MiB)
  bf16* P[6];
  for (int i = 0; i < 6; i++) P[i] = (bf16*)(ws + (size_t)(20 + i) * SLOT);
  bf16* Q[3];
  for (int i = 0; i < 3; i++) Q[i] = (bf16*)(ws + (size_t)(26 + i) * SLOT);
  bf16* Rb = (bf16*)(ws + 29 * SLOT);
  bf16* Fb = (bf16*)(ws + 30 * SLOT);          // total ws use: 62 MiB

  // 1) fused prep (W converts, W transposes, G)
  PrepArgs pa;
  const int rmIdx[5] = {1, 3, 5, 7, 8};
  for (int i = 0; i < 5; i++) { pa.cvt_src[i] = Wsrc + (size_t)rmIdx[i] * MAT; pa.cvt_dst[i] = Wrm[i]; }
  const int trIdx[6] = {0, 2, 4, 6, 8, 9};
  for (int i = 0; i < 6; i++) { pa.tr_src[i] = Wsrc + (size_t)trIdx[i] * MAT; pa.tr_dst[i] = Wt[i]; }
  pa.Wdec = Wdec; pa.praw = praw; pa.Gbf = Gbf;
  prep_all<<<dim3(5120), 256, 0, stream>>>(pa);

  // 2) L1: 6 GEMMs (384 blocks) + xcvt units [0,2048) as 256 8-unit blocks
  TreeArgs L1{};
  const bf16* l1a[6] = {Gbf, Wt[4], Wrm[3], Wt[2], Wrm[1], Wt[0]};
  const bf16* l1b[6] = {Wt[5], Wrm[4], Wt[3], Wrm[2], Wt[1], Wrm[0]};
  for (int i = 0; i < 6; i++) { L1.A[i] = l1a[i]; L1.B[i] = l1b[i]; L1.C[i] = P[i]; }
  L1.nG = 6; L1.x = x; L1.xbf = xbf; L1.ubase = 0;
  tree_level<<<dim3(384 + 256), 256, 0, stream>>>(L1);

  // 3) L2: Q0=NT(P0,P1) Q1t=NT(P3,P2) Q2t=NT(P5,P4) + xcvt units [2048,3072)
  TreeArgs L2{};
  const bf16* l2a[3] = {P[0], P[3], P[5]};
  const bf16* l2b[3] = {P[1], P[2], P[4]};
  for (int i = 0; i < 3; i++) { L2.A[i] = l2a[i]; L2.B[i] = l2b[i]; L2.C[i] = Q[i]; }
  L2.nG = 3; L2.x = x; L2.xbf = xbf; L2.ubase = 2048;
  tree_level<<<dim3(192 + 128), 256, 0, stream>>>(L2);

  // 4) L3: R = NT(Q0, Q1t) as 128 x 128x64-tiles + xcvt units [3072,3584)
  TreeArgs L3{};
  L3.A[0] = Q[0]; L3.B[0] = Q[1]; L3.C[0] = Rb;
  L3.nG = 1; L3.x = x; L3.xbf = xbf; L3.ubase = 3072;
  tree_level_hn<<<dim3(128 + 64), 256, 0, stream>>>(L3);

  // 5) L4: F = NT(R, Q2t) as 128 x 128x64-tiles + xcvt units [3584,4096)
  TreeArgs L4{};
  L4.A[0] = Rb; L4.B[0] = Q[2]; L4.C[0] = Fb;
  L4.nG = 1; L4.x = x; L4.xbf = xbf; L4.ubase = 3584;
  tree_level_hn<<<dim3(128 + 64), 256, 0, stream>>>(L4);

  // 6) out = NT(x, F), fp32 out (XCD-swizzled flat grid, unchanged R0)
  final_gemm<<<dim3(512), 256, 0, stream>>>(xbf, Fb, out);

  (void)in_sizes; (void)n_in; (void)out_size; (void)ws_size;
}

// Round 7
// 192.200 us; speedup vs baseline: 1.1169x; 1.0055x over previous
//
#include <hip/hip_runtime.h>
#include <stdint.h>
#include <stddef.h>

typedef __bf16 bf16;
typedef __bf16 bf16x8 __attribute__((ext_vector_type(8)));
typedef float f32x4 __attribute__((ext_vector_type(4)));

// ---------------------------------------------------------------------------
// async global->LDS, 16B per lane. LDS dest is wave-uniform base + lane*16.
// ---------------------------------------------------------------------------
__device__ __forceinline__ void global_to_lds16(const void* g, void* l) {
  const __attribute__((address_space(1))) unsigned* gp =
      reinterpret_cast<const __attribute__((address_space(1))) unsigned*>(
          reinterpret_cast<uintptr_t>(g));
  __attribute__((address_space(3))) unsigned* lp =
      reinterpret_cast<__attribute__((address_space(3))) unsigned*>(
          reinterpret_cast<uintptr_t>(l));
  __builtin_amdgcn_global_load_lds(gp, lp, 16, 0, 0);
}

// ---------------------------------------------------------------------------
// XCD-aware tile swizzle for 64-tile (8x8) GEMMs.
// ---------------------------------------------------------------------------
__device__ __forceinline__ void tile8x8_swizzle(int t, int& bx, int& by) {
  bx = (((t >> 3) & 1) << 2) | (t & 3);
  by = (((t >> 4) & 3) << 1) | ((t >> 2) & 1);
}

// ---------------------------------------------------------------------------
// 128x128-tile NT GEMM body, BK=64, PING-PONG double-buffered LDS (64 KB).
// R0 PROVEN BODY (197 us baseline) -- byte-for-byte unchanged.
// ---------------------------------------------------------------------------
template <typename OutT>
__device__ __forceinline__ void gemm128_body(const bf16* __restrict__ A,
                                             const bf16* __restrict__ B,
                                             OutT* __restrict__ C,
                                             int bx, int by) {
  __shared__ bf16 As[2][128 * 64];   // [buf][half*4096 + row*32 + col]
  __shared__ bf16 Bs[2][128 * 64];

  const int tid = threadIdx.x;
  const int wave = tid >> 6, lane = tid & 63;
  const int quad = lane >> 4, l16 = lane & 15;
  const int rowBase = by * 128;
  const int colBase = bx * 128;
  const int waveM = (wave >> 1) * 64, waveN = (wave & 1) * 64;

  // staging map: thread t covers global row t/4, cols (t&3)*8 .. +7
  const int sr = tid >> 2;
  const int sc = (tid & 3) * 8;
  const bf16* Ag0 = A + (size_t)(rowBase + sr) * 1024 + sc;   // rows 0..63
  const bf16* Ag1 = Ag0 + (size_t)64 * 1024;                  // rows 64..127
  const bf16* Bg0 = B + (size_t)(colBase + sr) * 1024 + sc;
  const bf16* Bg1 = Bg0 + (size_t)64 * 1024;

  const int woff = wave * 1024;  // byte offset of this wave's 16-row slab

  auto issue = [&](int k0, int p) {
    char* aB = (char*)As[p] + woff;
    char* bB = (char*)Bs[p] + woff;
    global_to_lds16(Ag0 + k0,      aB);             // half0 rows 0..63
    global_to_lds16(Ag1 + k0,      aB + 4096);      // half0 rows 64..127
    global_to_lds16(Ag0 + k0 + 32, aB + 8192);      // half1 rows 0..63
    global_to_lds16(Ag1 + k0 + 32, aB + 12288);     // half1 rows 64..127
    global_to_lds16(Bg0 + k0,      bB);
    global_to_lds16(Bg1 + k0,      bB + 4096);
    global_to_lds16(Bg0 + k0 + 32, bB + 8192);
    global_to_lds16(Bg1 + k0 + 32, bB + 12288);
  };

  f32x4 acc[4][4] = {};

  issue(0, 0);
  int p = 0;
#pragma unroll 1
  for (int k0 = 0; k0 < 1024; k0 += 64, p ^= 1) {
    __syncthreads();                 // drains loads for tile k0 (buf p)
    if (k0 + 64 < 1024) issue(k0 + 64, p ^ 1);   // prefetch into other buf
#pragma unroll
    for (int kk = 0; kk < 2; kk++) {
      const bf16* base = As[p] + kk * 4096;
      const bf16* baseB = Bs[p] + kk * 4096;
      bf16x8 af[4], bfr[4];
#pragma unroll
      for (int mi = 0; mi < 4; mi++)
        af[mi] = *(const bf16x8*)(base + (waveM + mi * 16 + l16) * 32 + quad * 8);
#pragma unroll
      for (int ni = 0; ni < 4; ni++)
        bfr[ni] = *(const bf16x8*)(baseB + (waveN + ni * 16 + l16) * 32 + quad * 8);
#pragma unroll
      for (int mi = 0; mi < 4; mi++)
#pragma unroll
        for (int ni = 0; ni < 4; ni++)
          acc[mi][ni] = __builtin_amdgcn_mfma_f32_16x16x32_bf16(af[mi], bfr[ni],
                                                                acc[mi][ni], 0, 0, 0);
    }
  }

  OutT* Cb = C + (size_t)(rowBase + waveM) * 1024 + colBase + waveN;
#pragma unroll
  for (int mi = 0; mi < 4; mi++)
#pragma unroll
    for (int ni = 0; ni < 4; ni++)
#pragma unroll
      for (int r = 0; r < 4; r++)
        Cb[(size_t)(mi * 16 + quad * 4 + r) * 1024 + ni * 16 + l16] =
            (OutT)acc[mi][ni][r];
}

// ---------------------------------------------------------------------------
// 128x64-tile NT GEMM body (R6 WIN): gemm128_body with N-extent halved.
// 48 KB LDS -> 3 blocks/CU; L3/L4 get 128 blocks of coverage. Bit-identical
// accumulation chain to gemm128_body.
// ---------------------------------------------------------------------------
template <typename OutT>
__device__ __forceinline__ void gemm128x64_body(const bf16* __restrict__ A,
                                                const bf16* __restrict__ B,
                                                OutT* __restrict__ C,
                                                int bx, int by) {
  __shared__ bf16 As[2][128 * 64];   // 16 KB per buffer (unchanged)
  __shared__ bf16 Bs[2][64 * 64];    // 8 KB per buffer

  const int tid = threadIdx.x;
  const int wave = tid >> 6, lane = tid & 63;
  const int quad = lane >> 4, l16 = lane & 15;
  const int rowBase = by * 128;
  const int colBase = bx * 64;
  const int waveM = (wave >> 1) * 64;   // 0,64
  const int waveN = (wave & 1) * 32;    // 0,32

  const int sr = tid >> 2;
  const int sc = (tid & 3) * 8;
  const bf16* Ag0 = A + (size_t)(rowBase + sr) * 1024 + sc;   // rows 0..63
  const bf16* Ag1 = Ag0 + (size_t)64 * 1024;                  // rows 64..127
  const bf16* Bg0 = B + (size_t)(colBase + sr) * 1024 + sc;   // rows 0..63

  const int woff = wave * 1024;

  auto issue = [&](int k0, int p) {
    char* aB = (char*)As[p] + woff;
    char* bB = (char*)Bs[p] + woff;
    global_to_lds16(Ag0 + k0,      aB);             // half0 rows 0..63
    global_to_lds16(Ag1 + k0,      aB + 4096);      // half0 rows 64..127
    global_to_lds16(Ag0 + k0 + 32, aB + 8192);      // half1 rows 0..63
    global_to_lds16(Ag1 + k0 + 32, aB + 12288);     // half1 rows 64..127
    global_to_lds16(Bg0 + k0,      bB);             // half0 rows 0..63
    global_to_lds16(Bg0 + k0 + 32, bB + 4096);      // half1 rows 0..63
  };

  f32x4 acc[4][2] = {};

  issue(0, 0);
  int p = 0;
#pragma unroll 1
  for (int k0 = 0; k0 < 1024; k0 += 64, p ^= 1) {
    __syncthreads();
    if (k0 + 64 < 1024) issue(k0 + 64, p ^ 1);
#pragma unroll
    for (int kk = 0; kk < 2; kk++) {
      const bf16* base = As[p] + kk * 4096;
      const bf16* baseB = Bs[p] + kk * 2048;
      bf16x8 af[4], bfr[2];
#pragma unroll
      for (int mi = 0; mi < 4; mi++)
        af[mi] = *(const bf16x8*)(base + (waveM + mi * 16 + l16) * 32 + quad * 8);
#pragma unroll
      for (int ni = 0; ni < 2; ni++)
        bfr[ni] = *(const bf16x8*)(baseB + (waveN + ni * 16 + l16) * 32 + quad * 8);
#pragma unroll
      for (int mi = 0; mi < 4; mi++)
#pragma unroll
        for (int ni = 0; ni < 2; ni++)
          acc[mi][ni] = __builtin_amdgcn_mfma_f32_16x16x32_bf16(af[mi], bfr[ni],
                                                                acc[mi][ni], 0, 0, 0);
    }
  }

  OutT* Cb = C + (size_t)(rowBase + waveM) * 1024 + colBase + waveN;
#pragma unroll
  for (int mi = 0; mi < 4; mi++)
#pragma unroll
    for (int ni = 0; ni < 2; ni++)
#pragma unroll
      for (int r = 0; r < 4; r++)
        Cb[(size_t)(mi * 16 + quad * 4 + r) * 1024 + ni * 16 + l16] =
            (OutT)acc[mi][ni][r];
}

// ---------------------------------------------------------------------------
// 256x128-tile NT GEMM body (R3 harness-verified). BK=64, ping-pong LDS
// (96 KB -> 1 block/CU), 512 threads = 8 waves (4M x 2N), wave tile 64x64.
// 24 B staged per output element (vs 32 for 128x128): used ONLY for the
// bytes-bound final GEMM (stages 192 MB vs 256 MB). XOR-granule LDS swizzle
// (rule 21: linear LDS dest, inverse-swizzled global source, swizzled
// ds_read) -> conflict-free reads. Ascending-K chain -> accumulation
// bit-identical to gemm128_body outputs.
// ---------------------------------------------------------------------------
template <typename OutT>
__device__ __forceinline__ void gemm256x128_body(const bf16* __restrict__ A,
                                                 const bf16* __restrict__ B,
                                                 OutT* __restrict__ C,
                                                 int bx, int by) {
  __shared__ bf16 As[2][256 * 64];   // 32 KB per buffer
  __shared__ bf16 Bs[2][128 * 64];   // 16 KB per buffer

  const int tid = threadIdx.x;            // 0..511
  const int wave = tid >> 6, lane = tid & 63;
  const int quad = lane >> 4, l16 = lane & 15;
  const int rowBase = by * 256;
  const int colBase = bx * 128;
  const int waveM = (wave >> 1) * 64;     // 0,64,128,192
  const int waveN = (wave & 1) * 64;      // 0,64

  // staging map: one call = 512 threads x 16B = 8 KB = 64 rows of 128 B.
  // lane covers row (call*64 + wave*8 + (lane>>3)); source granule is
  // pre-swizzled: (lane&7) ^ (row&7), and row&7 == lane>>3 here.
  const int srow = tid >> 3;                                  // 0..63
  const int scol = (((tid & 7) ^ ((tid >> 3) & 7)) << 3);     // bf16 offset
  const bf16* Ag = A + (size_t)(rowBase + srow) * 1024 + scol;
  const bf16* Bg = B + (size_t)(colBase + srow) * 1024 + scol;
  const int ldsoff = wave * 1024;         // wave's 1 KB slab within a call

  auto issue = [&](int k0, int p) {
    char* aB = (char*)As[p] + ldsoff;
    char* bB = (char*)Bs[p] + ldsoff;
#pragma unroll
    for (int c = 0; c < 4; c++)           // A: 4 calls x 64 rows
      global_to_lds16(Ag + k0 + (size_t)c * 64 * 1024, aB + c * 8192);
#pragma unroll
    for (int c = 0; c < 2; c++)           // B: 2 calls x 64 rows
      global_to_lds16(Bg + k0 + (size_t)c * 64 * 1024, bB + c * 8192);
  };

  f32x4 acc[4][4] = {};

  issue(0, 0);
  int p = 0;
  const int swz = l16 & 7;
#pragma unroll 1
  for (int k0 = 0; k0 < 1024; k0 += 64, p ^= 1) {
    __syncthreads();                 // drains loads for tile k0 (buf p)
    if (k0 + 64 < 1024) issue(k0 + 64, p ^ 1);   // prefetch into other buf
#pragma unroll
    for (int kk = 0; kk < 2; kk++) {
      bf16x8 af[4], bfr[4];
#pragma unroll
      for (int mi = 0; mi < 4; mi++) {
        const int row = waveM + mi * 16 + l16;
        const int g = ((kk << 2) + quad) ^ swz;   // row&7 == l16&7
        af[mi] = *(const bf16x8*)(As[p] + row * 64 + g * 8);
      }
#pragma unroll
      for (int ni = 0; ni < 4; ni++) {
        const int row = waveN + ni * 16 + l16;
        const int g = ((kk << 2) + quad) ^ swz;
        bfr[ni] = *(const bf16x8*)(Bs[p] + row * 64 + g * 8);
      }
#pragma unroll
      for (int mi = 0; mi < 4; mi++)
#pragma unroll
        for (int ni = 0; ni < 4; ni++)
          acc[mi][ni] = __builtin_amdgcn_mfma_f32_16x16x32_bf16(af[mi], bfr[ni],
                                                                acc[mi][ni], 0, 0, 0);
    }
  }

  OutT* Cb = C + (size_t)(rowBase + waveM) * 1024 + colBase + waveN;
#pragma unroll
  for (int mi = 0; mi < 4; mi++)
#pragma unroll
    for (int ni = 0; ni < 4; ni++)
#pragma unroll
      for (int r = 0; r < 4; r++)
        Cb[(size_t)(mi * 16 + quad * 4 + r) * 1024 + ni * 16 + l16] =
            (OutT)acc[mi][ni][r];
}

// ---------------------------------------------------------------------------
// fused prep kernel (unchanged R0). Flat grid of 5120 independent blocks.
// ---------------------------------------------------------------------------
struct PrepArgs {
  const float* cvt_src[5]; bf16* cvt_dst[5];
  const float* tr_src[6];  bf16* tr_dst[6];
  const float* Wdec; const int* praw; bf16* Gbf;
};

__global__ __launch_bounds__(256) void prep_all(PrepArgs p) {
  __shared__ alignas(16) char smem[64 * 65 * 2];
  const int b = blockIdx.x;
  const int tid = threadIdx.x;

  if (b < 2560) {  // ---- convert row-major W ----
    const int m = b >> 9, blk = b & 511;
    const float* __restrict__ src = p.cvt_src[m];
    bf16* __restrict__ dst = p.cvt_dst[m];
    const int i = (blk * 256 + tid) * 8;
    float4 a = *(const float4*)(src + i);
    float4 c = *(const float4*)(src + i + 4);
    bf16x8 o;
    o[0] = (bf16)a.x; o[1] = (bf16)a.y; o[2] = (bf16)a.z; o[3] = (bf16)a.w;
    o[4] = (bf16)c.x; o[5] = (bf16)c.y; o[6] = (bf16)c.z; o[7] = (bf16)c.w;
    *(bf16x8*)(dst + i) = o;
  } else if (b < 4096) {  // ---- transpose+convert W ----
    const int t = b - 2560;
    const int m = t >> 8, r = t & 255;
    const float* __restrict__ src = p.tr_src[m];
    bf16* __restrict__ dst = p.tr_dst[m];
    bf16(*tile)[65] = reinterpret_cast<bf16(*)[65]>(smem);
    const int bx = (r & 15) * 64;
    const int by = (r >> 4) * 64;
    const int tx = tid & 63;
    const int ty4 = tid >> 6;
#pragma unroll
    for (int rr = 0; rr < 16; rr++) {
      int row = ty4 * 16 + rr;
      tile[row][tx] = (bf16)src[(size_t)(by + row) * 1024 + bx + tx];
    }
    __syncthreads();
#pragma unroll
    for (int rr = 0; rr < 16; rr++) {
      int row = ty4 * 16 + rr;
      dst[(size_t)(bx + row) * 1024 + by + tx] = tile[tx][row];
    }
  } else {  // ---- G build: G[j,d] = sum_{k: perm[k]==d} W_dec[j,k] ----
    const int j = b - 4096;
    float* row = (float*)smem;
    int* perm_l = (int*)(smem + 4096);
    int* nzp = (int*)(smem + 4096 + 1024);
#pragma unroll
    for (int c = 0; c < 4; c++) row[tid * 4 + c] = 0.f;
    if (tid == 0) *nzp = 0;
    __syncthreads();
    // int64 little-endian perm has all-zero high words.
    if (tid < 128 && p.praw[2 * tid + 1] != 0) atomicOr(nzp, 1);
    __syncthreads();
    const int is64 = (*nzp == 0);
    perm_l[tid] = is64 ? p.praw[2 * tid] : p.praw[tid];
    __syncthreads();
    atomicAdd(&row[perm_l[tid]], p.Wdec[(size_t)j * 256 + tid]);
    __syncthreads();
#pragma unroll
    for (int c = 0; c < 4; c++)
      p.Gbf[(size_t)j * 1024 + tid * 4 + c] = (bf16)row[tid * 4 + c];
  }
}

// ---------------------------------------------------------------------------
// Tree-level kernel (unchanged R0): blocks [0, nG*64) do batched 128x128-tile
// NT GEMMs with XCD-aware tile swizzle; blocks >= nG*64 each convert EIGHT
// 2048-float x-units fp32->bf16.
// ---------------------------------------------------------------------------
struct TreeArgs {
  const bf16* A[6]; const bf16* B[6]; bf16* C[6];
  int nG;
  const float* x; bf16* xbf; int ubase;
};

__global__ __launch_bounds__(256) void tree_level(TreeArgs a) {
  const int b = blockIdx.x;
  const int gBlocks = a.nG * 64;
  if (b < gBlocks) {
    const int z = b >> 6, t = b & 63;
    int bx, by;
    tile8x8_swizzle(t, bx, by);
    gemm128_body<bf16>(a.A[z], a.B[z], a.C[z], bx, by);
  } else {
    const int u0 = a.ubase + (b - gBlocks) * 8;
#pragma unroll
    for (int u = 0; u < 8; u++) {
      const int i = (u0 + u) * 2048 + (int)threadIdx.x * 8;
      float4 v0 = *(const float4*)(a.x + i);
      float4 v1 = *(const float4*)(a.x + i + 4);
      bf16x8 o;
      o[0] = (bf16)v0.x; o[1] = (bf16)v0.y; o[2] = (bf16)v0.z; o[3] = (bf16)v0.w;
      o[4] = (bf16)v1.x; o[5] = (bf16)v1.y; o[6] = (bf16)v1.z; o[7] = (bf16)v1.w;
      *(bf16x8*)(a.xbf + i) = o;
    }
  }
}

// ---------------------------------------------------------------------------
// Half-N tree-level kernel for L3/L4 (R6 WIN, unchanged): blocks [0,128) do
// one 1024^2 NT GEMM as 128x64 tiles (3 blocks/CU, 2x coverage); blocks
// >= 128 do x-convert filler.
// ---------------------------------------------------------------------------
__global__ __launch_bounds__(256) void tree_level_hn(TreeArgs a) {
  const int b = blockIdx.x;
  if (b < 128) {
    gemm128x64_body<bf16>(a.A[0], a.B[0], a.C[0], b >> 3, b & 7);
  } else {
    const int u0 = a.ubase + (b - 128) * 8;
#pragma unroll
    for (int u = 0; u < 8; u++) {
      const int i = (u0 + u) * 2048 + (int)threadIdx.x * 8;
      float4 v0 = *(const float4*)(a.x + i);
      float4 v1 = *(const float4*)(a.x + i + 4);
      bf16x8 o;
      o[0] = (bf16)v0.x; o[1] = (bf16)v0.y; o[2] = (bf16)v0.z; o[3] = (bf16)v0.w;
      o[4] = (bf16)v1.x; o[5] = (bf16)v1.y; o[6] = (bf16)v1.z; o[7] = (bf16)v1.w;
      *(bf16x8*)(a.xbf + i) = o;
    }
  }
}

// ---------------------------------------------------------------------------
// Final: out = x * F^T, fp32 out. M=8192, N=1024, K=1024. 256x128 tiles ->
// 256 blocks = exactly 1 block/CU, zero tail, 8 waves/CU. Staged bytes
// 192 MB (vs 256 MB at 128x128): this dispatch is bytes-bound at the ~7 TB/s
// effective staging ceiling (R1 PMC), so -25% bytes is the lever.
// XCD mapping: b%8 = XCD k owns by-panels {4k..4k+3} (2 MB of A) + all of
// F (2 MB) = 4 MB working set, fits its private L2.
// ---------------------------------------------------------------------------
__global__ __launch_bounds__(512) void final_gemm(const bf16* __restrict__ A,
                                                  const bf16* __restrict__ B,
                                                  float* __restrict__ C) {
  const int b = blockIdx.x;
  const int j = b >> 3;
  const int by = (b & 7) * 4 + (j & 3);
  const int bx = j >> 2;
  gemm256x128_body<float>(A, B, C, bx, by);
}

// ---------------------------------------------------------------------------
// Host launcher.  6 kernels.
// out = x @ (G * W9 * W8 * W8 * W7 * W6 * W5 * W4 * W3 * W2 * W1 * W0)^T
// Tree: P0=G*W9  P1=(W8*W8)^T  P2=W7*W6  P3=(W5*W4)^T  P4=W3*W2  P5=(W1*W0)^T
//       Q0=NT(P0,P1) Q1t=NT(P3,P2) Q2t=NT(P5,P4); R=NT(Q0,Q1t); F=NT(R,Q2t)
//       out = NT(x, F).
// x convert filler: 2048 units in L1, 1024 in L2, 512 in L3, 512 in L4.
// ---------------------------------------------------------------------------
extern "C" void kernel_launch(void* const* d_in, const int* in_sizes, int n_in,
                              void* d_out, int out_size, void* d_ws, size_t ws_size,
                              hipStream_t stream) {
  const float* x    = (const float*)d_in[0];
  const float* Wsrc = (const float*)d_in[1];   // 10 x 1024 x 1024
  const float* Wdec = (const float*)d_in[2];   // 1024 x 256
  const int*   praw = (const int*)d_in[3];
  float* out = (float*)d_out;

  constexpr size_t MAT  = 1024ull * 1024ull;
  constexpr size_t SLOT = 2ull * 1024 * 1024;  // 2 MiB = one bf16 DxD matrix

  char* ws = (char*)d_ws;
  bf16* Wrm[5];  // W1, W3, W5, W7, W8 (row-major bf16)
  for (int i = 0; i < 5; i++) Wrm[i] = (bf16*)(ws + (size_t)i * SLOT);
  bf16* Wt[6];   // W0^T, W2^T, W4^T, W6^T, W8^T, W9^T
  for (int i = 0; i < 6; i++) Wt[i] = (bf16*)(ws + (size_t)(5 + i) * SLOT);
  bf16* Gbf = (bf16*)(ws + 11 * SLOT);
  bf16* xbf = (bf16*)(ws + 12 * SLOT);         // 8 slots (16 MiB)
  bf16* P[6];
  for (int i = 0; i < 6; i++) P[i] = (bf16*)(ws + (size_t)(20 + i) * SLOT);
  bf16* Q[3];
  for (int i = 0; i < 3; i++) Q[i] = (bf16*)(ws + (size_t)(26 + i) * SLOT);
  bf16* Rb = (bf16*)(ws + 29 * SLOT);
  bf16* Fb = (bf16*)(ws + 30 * SLOT);          // total ws use: 62 MiB

  // 1) fused prep (W converts, W transposes, G)
  PrepArgs pa;
  const int rmIdx[5] = {1, 3, 5, 7, 8};
  for (int i = 0; i < 5; i++) { pa.cvt_src[i] = Wsrc + (size_t)rmIdx[i] * MAT; pa.cvt_dst[i] = Wrm[i]; }
  const int trIdx[6] = {0, 2, 4, 6, 8, 9};
  for (int i = 0; i < 6; i++) { pa.tr_src[i] = Wsrc + (size_t)trIdx[i] * MAT; pa.tr_dst[i] = Wt[i]; }
  pa.Wdec = Wdec; pa.praw = praw; pa.Gbf = Gbf;
  prep_all<<<dim3(5120), 256, 0, stream>>>(pa);

  // 2) L1: 6 GEMMs (384 blocks) + xcvt units [0,2048) as 256 8-unit blocks
  TreeArgs L1{};
  const bf16* l1a[6] = {Gbf, Wt[4], Wrm[3], Wt[2], Wrm[1], Wt[0]};
  const bf16* l1b[6] = {Wt[5], Wrm[4], Wt[3], Wrm[2], Wt[1], Wrm[0]};
  for (int i = 0; i < 6; i++) { L1.A[i] = l1a[i]; L1.B[i] = l1b[i]; L1.C[i] = P[i]; }
  L1.nG = 6; L1.x = x; L1.xbf = xbf; L1.ubase = 0;
  tree_level<<<dim3(384 + 256), 256, 0, stream>>>(L1);

  // 3) L2: Q0=NT(P0,P1) Q1t=NT(P3,P2) Q2t=NT(P5,P4) + xcvt units [2048,3072)
  TreeArgs L2{};
  const bf16* l2a[3] = {P[0], P[3], P[5]};
  const bf16* l2b[3] = {P[1], P[2], P[4]};
  for (int i = 0; i < 3; i++) { L2.A[i] = l2a[i]; L2.B[i] = l2b[i]; L2.C[i] = Q[i]; }
  L2.nG = 3; L2.x = x; L2.xbf = xbf; L2.ubase = 2048;
  tree_level<<<dim3(192 + 128), 256, 0, stream>>>(L2);

  // 4) L3: R = NT(Q0, Q1t) as 128 x 128x64-tiles + xcvt units [3072,3584)
  TreeArgs L3{};
  L3.A[0] = Q[0]; L3.B[0] = Q[1]; L3.C[0] = Rb;
  L3.nG = 1; L3.x = x; L3.xbf = xbf; L3.ubase = 3072;
  tree_level_hn<<<dim3(128 + 64), 256, 0, stream>>>(L3);

  // 5) L4: F = NT(R, Q2t) as 128 x 128x64-tiles + xcvt units [3584,4096)
  TreeArgs L4{};
  L4.A[0] = Rb; L4.B[0] = Q[2]; L4.C[0] = Fb;
  L4.nG = 1; L4.x = x; L4.xbf = xbf; L4.ubase = 3584;
  tree_level_hn<<<dim3(128 + 64), 256, 0, stream>>>(L4);

  // 6) out = NT(x, F), fp32 out (256 blocks of 256x128, XCD-partitioned)
  final_gemm<<<dim3(256), 512, 0, stream>>>(xbf, Fb, out);

  (void)in_sizes; (void)n_in; (void)out_size; (void)ws_size;
}